// Round 4
// baseline (303.070 us; speedup 1.0000x reference)
//
#include <hip/hip_runtime.h>
#include <hip/hip_cooperative_groups.h>

// Problem constants: bt=4, nv=20000, nf=40000, H=W=256, S=2048
#define BT   4
#define NV   20000
#define NF   40000
#define SMP  2048
#define NPIX (BT * 256 * 256)
#define NVG  (BT * NV)            // 80000
#define NBLK 512                  // 2 blocks/CU, cooperative co-resident
#define NTH  256
#define NCH  128                  // vertex chunks per batch (NBLK = NCH*BT)
#define CHUNK 157                 // ceil(NV/NCH); 127*157=19939, last chunk=61
#define P    8                    // samples per thread (256*8 = 2048)

namespace cg = cooperative_groups;

__global__ __launch_bounds__(NTH) void fused_k(
    const float*  __restrict__ verts,     // (4,20000,3)
    const float4* __restrict__ bds,       // (4,2048,4) {x,y,z,mask}
    const int*    __restrict__ faces,     // (4,40000,3)
    const int4*   __restrict__ p2f,       // (4,256,256,1) as int4 quads
    float*        __restrict__ out,
    float*        __restrict__ visible,   // ws: 80000 f32
    int*          __restrict__ flags,     // ws: 4 ints
    float*        __restrict__ mnOut,     // ws: [NCH][BT][SMP] f32 = 4 MB
    float*        __restrict__ partials)  // ws: 512 f32
{
    cg::grid_group grid = cg::this_grid();
    const int tid  = threadIdx.x;
    const int gid  = blockIdx.x;
    const int gtid = gid * NTH + tid;

    __shared__ float4 shv[CHUNK];
    __shared__ float  shred[NTH];

    // ---- phase 0: zero visible + flags (don't trust ws poison semantics)
    if (gtid < NVG) visible[gtid] = 0.0f;
    if (gtid < BT)  flags[gtid]   = 0;
    grid.sync();

    // ---- phase 1: visibility scatter, 4 pixels per thread
    if (gtid < NPIX / 4) {
        int4 f4 = p2f[gtid];
        int fs[4] = {f4.x, f4.y, f4.z, f4.w};
        #pragma unroll
        for (int k = 0; k < 4; ++k) {
            int fi = fs[k];
            if (fi >= 0) {
                int b    = fi / NF;
                int base = fi * 3;
                int off  = b * NV;
                visible[faces[base + 0] + off] = 1.0f;  // idempotent racy
                visible[faces[base + 1] + off] = 1.0f;
                visible[faces[base + 2] + off] = 1.0f;
            }
        }
    }
    grid.sync();

    // ---- phase 2: pack own chunk into LDS, min over chunk for 2048 samples
    const int b  = gid >> 7;            // gid = b*NCH + c
    const int c  = gid & (NCH - 1);
    const int v0 = c * CHUNK;
    const int cnt = min(CHUNK, NV - v0);   // 157 or 61

    float px[P], py[P], pz[P], mn[P];
    #pragma unroll
    for (int u = 0; u < P; ++u) {          // L2-hit loads, issued early
        float4 p = bds[b * SMP + u * NTH + tid];
        px[u] = p.x; py[u] = p.y; pz[u] = p.z;
        mn[u] = 3.0e38f;
    }
    if (tid < cnt) {
        int vi = b * NV + v0 + tid;
        float x = verts[3 * vi + 0];
        float y = verts[3 * vi + 1];
        float z = verts[3 * vi + 2];
        float w;
        if (visible[vi] > 0.0f) {
            w = x * x + y * y + z * z;     // q = |v|^2 - 2<p,v>; +|p|^2 later
        } else {
            w = 1e30f;                     // never wins the min
            flags[b] = 1;                  // racy idempotent
        }
        shv[tid] = make_float4(-2.f * x, -2.f * y, -2.f * z, w);
    }
    __syncthreads();
    #pragma unroll 4
    for (int j = 0; j < cnt; ++j) {
        float4 v = shv[j];                 // LDS broadcast
        #pragma unroll
        for (int u = 0; u < P; ++u) {
            float q = fmaf(px[u], v.x,
                      fmaf(py[u], v.y,
                      fmaf(pz[u], v.z, v.w)));
            mn[u] = fminf(mn[u], q);
        }
    }
    {
        float* dst = mnOut + (c * BT + b) * SMP;
        #pragma unroll
        for (int u = 0; u < P; ++u)
            dst[u * NTH + tid] = mn[u];    // coalesced, no atomics
    }
    grid.sync();

    // ---- phase 3: per-sample min over NCH chunks + block partial masked sum
    {
        const int sloc = tid & 15;         // 16 samples per block
        const int cslc = tid >> 4;         // 16 slices x 8 chunks each
        const int i    = gid * 16 + sloc;  // global sample 0..8191
        const int bb   = i >> 11;
        const int ss   = i & (SMP - 1);
        float v = 3.0e38f;
        #pragma unroll
        for (int k = 0; k < 8; ++k) {
            int cc = cslc * 8 + k;
            v = fminf(v, mnOut[(cc * BT + bb) * SMP + ss]);
        }
        shred[tid] = v;
        __syncthreads();
        float contrib = 0.0f;
        if (tid < 16) {
            float m = shred[tid];
            #pragma unroll
            for (int k = 1; k < 16; ++k) m = fminf(m, shred[tid + 16 * k]);
            float4 p = bds[i];             // i uses sloc == tid here
            float bs = fmaf(p.x, p.x, fmaf(p.y, p.y, p.z * p.z));
            float mnv = m + bs;            // true min d2
            if (flags[bb]) mnv = fminf(mnv, 1000.0f);  // exact MASK_PENALTY
            contrib = mnv * p.w;           // p.w = sample mask
        }
        #pragma unroll
        for (int o = 8; o > 0; o >>= 1)
            contrib += __shfl_down(contrib, o, 64);   // lanes >=16 hold 0
        if (tid == 0) partials[gid] = contrib;
    }
    grid.sync();

    // ---- phase 4: block 0 reduces 512 partials
    if (gid == 0) {
        float s = partials[tid] + partials[tid + NTH];
        #pragma unroll
        for (int o = 32; o > 0; o >>= 1) s += __shfl_down(s, o, 64);
        if ((tid & 63) == 0) shred[tid >> 6] = s;
        __syncthreads();
        if (tid == 0)
            out[0] = (shred[0] + shred[1] + shred[2] + shred[3]) / (float)BT;
    }
}

extern "C" void kernel_launch(void* const* d_in, const int* in_sizes, int n_in,
                              void* d_out, int out_size, void* d_ws, size_t ws_size,
                              hipStream_t stream) {
    const float*  verts = (const float*)d_in[0];
    const float4* bds   = (const float4*)d_in[1];
    const int*    faces = (const int*)d_in[2];
    const int4*   p2f   = (const int4*)d_in[3];
    float*        out   = (float*)d_out;

    char* ws = (char*)d_ws;
    float* mnOut    = (float*)ws;                          // 4,194,304 B
    float* visible  = (float*)(ws + 4194304);              //   320,000 B
    int*   flags    = (int*)(ws + 4194304 + 320000);       //        16 B
    float* partials = (float*)(ws + 4194304 + 320000 + 64);//     2,048 B

    void* args[] = { (void*)&verts, (void*)&bds, (void*)&faces, (void*)&p2f,
                     (void*)&out, (void*)&visible, (void*)&flags,
                     (void*)&mnOut, (void*)&partials };
    hipLaunchCooperativeKernel((void*)fused_k, dim3(NBLK), dim3(NTH),
                               args, 0, stream);
}

// Round 5
// 101.489 us; speedup vs baseline: 2.9862x; 2.9862x over previous
//
#include <hip/hip_runtime.h>

// Problem constants: bt=4, nv=20000, nf=40000, H=W=256, S=2048
#define BT   4
#define NV   20000
#define NF   40000
#define SMP  2048
#define NPIX (BT * 256 * 256)
#define NVG  (BT * NV)            // 80000
#define NCH  128                  // vertex chunks per batch
#define NBLK (BT * NCH)           // 512 blocks = 2/CU
#define NTH  256
#define CHUNK 157                 // ceil(NV/NCH); last chunk = 61
#define P    8                    // samples per thread (256*8 = 2048)

// Order-preserving float<->uint encoding (q can be negative).
__device__ __forceinline__ unsigned int enc_f32(float f) {
    unsigned int u = __float_as_uint(f);
    return (u & 0x80000000u) ? ~u : (u | 0x80000000u);
}
__device__ __forceinline__ float dec_f32(unsigned int k) {
    unsigned int u = (k & 0x80000000u) ? (k & 0x7FFFFFFFu) : ~k;
    return __uint_as_float(u);
}

// 1) init: zero visible/flags/ticket, minKeys -> encoded +inf.
__global__ void init_k(float* __restrict__ visible,
                       unsigned int* __restrict__ flags,
                       unsigned int* __restrict__ minKeys,
                       unsigned int* __restrict__ cnt) {
    int i = blockIdx.x * blockDim.x + threadIdx.x;
    if (i < NVG)      visible[i] = 0.0f;
    if (i < BT * SMP) minKeys[i] = 0xFFFFFFFFu;
    if (i < BT)       flags[i]   = 0u;
    if (i == 0)       cnt[0]     = 0u;
}

// 2) visibility scatter: 4 pixels/thread -> face -> 3 vertices
__global__ void vis_k(const int4* __restrict__ p2f,
                      const int* __restrict__ faces,
                      float* __restrict__ visible) {
    int p = blockIdx.x * blockDim.x + threadIdx.x;   // < NPIX/4
    int4 f4 = p2f[p];
    int fs[4] = {f4.x, f4.y, f4.z, f4.w};
    #pragma unroll
    for (int k = 0; k < 4; ++k) {
        int fi = fs[k];
        if (fi >= 0) {
            int b    = fi / NF;
            int base = fi * 3;
            int off  = b * NV;
            visible[faces[base + 0] + off] = 1.0f;   // idempotent racy
            visible[faces[base + 1] + off] = 1.0f;
            visible[faces[base + 2] + off] = 1.0f;
        }
    }
}

// 3) mega: pack own chunk into LDS, P=8 min loop, atomicMin the encoded
//    keys; last-arriving block (ticket) finishes the loss. No grid.sync.
__global__ __launch_bounds__(NTH) void
mega_k(const float*  __restrict__ verts,
       const float4* __restrict__ bds,
       const float*  __restrict__ visible,
       unsigned int* __restrict__ flags,
       unsigned int* __restrict__ minKeys,
       unsigned int* __restrict__ cnt,
       float*        __restrict__ out) {
    __shared__ float4 shv[CHUNK];
    __shared__ bool   lastBlk;
    __shared__ float  part[4];

    const int tid = threadIdx.x;
    const int gid = blockIdx.x;
    const int b   = gid >> 7;            // gid = b*NCH + c
    const int c   = gid & (NCH - 1);
    const int v0  = c * CHUNK;
    const int cntv = min(CHUNK, NV - v0);   // 157 or 61

    // pack own chunk straight into LDS (no global packed[] round trip)
    if (tid < cntv) {
        int vi = b * NV + v0 + tid;
        float x = verts[3 * vi + 0];
        float y = verts[3 * vi + 1];
        float z = verts[3 * vi + 2];
        float w;
        if (visible[vi] > 0.0f) {
            w = x * x + y * y + z * z;   // q = |v|^2 - 2<p,v>; +|p|^2 later
        } else {
            w = 1e30f;                   // never wins the min
            atomicOr(&flags[b], 1u);     // device-scope, rare
        }
        shv[tid] = make_float4(-2.f * x, -2.f * y, -2.f * z, w);
    }

    float px[P], py[P], pz[P], mn[P];
    #pragma unroll
    for (int u = 0; u < P; ++u) {
        float4 p = bds[b * SMP + u * NTH + tid];
        px[u] = p.x; py[u] = p.y; pz[u] = p.z;
        mn[u] = 3.0e38f;
    }
    __syncthreads();

    #pragma unroll 4
    for (int j = 0; j < cntv; ++j) {
        float4 v = shv[j];               // LDS broadcast
        #pragma unroll
        for (int u = 0; u < P; ++u) {
            float q = fmaf(px[u], v.x,
                      fmaf(py[u], v.y,
                      fmaf(pz[u], v.z, v.w)));
            mn[u] = fminf(mn[u], q);
        }
    }
    #pragma unroll
    for (int u = 0; u < P; ++u)
        atomicMin(&minKeys[b * SMP + u * NTH + tid], enc_f32(mn[u]));

    // ticket: last block to finish does the final reduction
    __syncthreads();
    if (tid == 0) {
        __threadfence();
        lastBlk = (atomicAdd(cnt, 1u) == NBLK - 1);
    }
    __syncthreads();
    if (!lastBlk) return;

    // final: coherent atomic reads of keys, +|p|^2, penalty clamp, masked sum
    float sum = 0.0f;
    #pragma unroll
    for (int bb = 0; bb < BT; ++bb) {
        unsigned int fb = atomicOr(&flags[bb], 0u);   // coherent read
        for (int j = 0; j < SMP; j += NTH) {
            int i = bb * SMP + j + tid;
            unsigned int k = atomicAdd(&minKeys[i], 0u);  // coherent read
            float4 p = bds[i];
            float bs = fmaf(p.x, p.x, fmaf(p.y, p.y, p.z * p.z));
            float mnv = dec_f32(k) + bs;
            if (fb) mnv = fminf(mnv, 1000.0f);        // exact MASK_PENALTY
            sum = fmaf(mnv, p.w, sum);                // p.w = sample mask
        }
    }
    #pragma unroll
    for (int o = 32; o > 0; o >>= 1) sum += __shfl_down(sum, o, 64);
    if ((tid & 63) == 0) part[tid >> 6] = sum;
    __syncthreads();
    if (tid == 0)
        out[0] = (part[0] + part[1] + part[2] + part[3]) / (float)BT;
}

extern "C" void kernel_launch(void* const* d_in, const int* in_sizes, int n_in,
                              void* d_out, int out_size, void* d_ws, size_t ws_size,
                              hipStream_t stream) {
    const float*  verts = (const float*)d_in[0];   // (4,20000,3) f32
    const float4* bds   = (const float4*)d_in[1];  // (4,2048,4)  f32
    const int*    faces = (const int*)d_in[2];     // (4,40000,3) int
    const int4*   p2f   = (const int4*)d_in[3];    // (4,256,256,1) int
    float*        out   = (float*)d_out;

    char* ws = (char*)d_ws;
    float*        visible = (float*)ws;                       // 320,000 B
    unsigned int* minKeys = (unsigned int*)(ws + 320000);     //  32,768 B
    unsigned int* flags   = (unsigned int*)(ws + 352768);     //      16 B
    unsigned int* cnt     = (unsigned int*)(ws + 352784);     //       4 B

    init_k<<<(NVG + NTH - 1) / NTH, NTH, 0, stream>>>(visible, flags, minKeys, cnt);
    vis_k<<<(NPIX / 4) / NTH, NTH, 0, stream>>>((const int4*)p2f, faces, visible);
    mega_k<<<NBLK, NTH, 0, stream>>>(verts, bds, visible, flags, minKeys, cnt, out);
}

// Round 6
// 99.552 us; speedup vs baseline: 3.0443x; 1.0195x over previous
//
#include <hip/hip_runtime.h>

// Problem constants: bt=4, nv=20000, nf=40000, H=W=256, S=2048
#define BT   4
#define NV   20000
#define NF   40000
#define SMP  2048
#define NPIX (BT * 256 * 256)
#define NVG  (BT * NV)            // 80000
#define NCH  128                  // vertex chunks per batch
#define NBLK (BT * NCH)           // 512 blocks = 2/CU
#define NTH  256
#define CHUNK 157                 // ceil(NV/NCH); last chunk = 61
#define P    8                    // samples per thread (256*8 = 2048)
#define MAGIC 0x5ACE1234u         // "visible" marker; ws pre-state never matters

// Order-preserving float<->uint encoding (q can be negative).
__device__ __forceinline__ unsigned int enc_f32(float f) {
    unsigned int u = __float_as_uint(f);
    return (u & 0x80000000u) ? ~u : (u | 0x80000000u);
}
__device__ __forceinline__ float dec_f32(unsigned int k) {
    unsigned int u = (k & 0x80000000u) ? (k & 0x7FFFFFFFu) : ~k;
    return __uint_as_float(u);
}

// 1) visibility scatter (4 pixels/thread -> face -> 3 verts) + side-init of
//    minKeys/flags/cnt for the next kernel (kernel boundary orders it).
__global__ __launch_bounds__(NTH) void
vis_k(const int4* __restrict__ p2f,
      const int* __restrict__ faces,
      unsigned int* __restrict__ visible,
      unsigned int* __restrict__ minKeys,
      unsigned int* __restrict__ flags,
      unsigned int* __restrict__ cnt) {
    int p = blockIdx.x * blockDim.x + threadIdx.x;   // < NPIX/4 = 65536
    // side-init (no separate init kernel)
    if (p < BT * SMP) minKeys[p] = 0xFFFFFFFFu;
    if (p < BT)       flags[p]   = 0u;
    if (p == BT)      cnt[0]     = 0u;

    int4 f4 = p2f[p];
    int fs[4] = {f4.x, f4.y, f4.z, f4.w};
    #pragma unroll
    for (int k = 0; k < 4; ++k) {
        int fi = fs[k];
        if (fi >= 0) {
            int b    = fi / NF;
            int base = fi * 3;
            int off  = b * NV;
            visible[faces[base + 0] + off] = MAGIC;   // idempotent racy
            visible[faces[base + 1] + off] = MAGIC;
            visible[faces[base + 2] + off] = MAGIC;
        }
    }
}

// 2) mega: pack own chunk into LDS, P=8 min loop, atomicMin encoded keys;
//    last-arriving block (ticket) finalizes the loss.
__global__ __launch_bounds__(NTH) void
mega_k(const float*  __restrict__ verts,
       const float4* __restrict__ bds,
       const unsigned int* __restrict__ visible,
       unsigned int* __restrict__ flags,
       unsigned int* __restrict__ minKeys,
       unsigned int* __restrict__ cnt,
       float*        __restrict__ out) {
    __shared__ float4 shv[CHUNK];
    __shared__ bool   lastBlk;
    __shared__ float  part[4];

    const int tid = threadIdx.x;
    const int b   = blockIdx.z;
    const int c   = blockIdx.x;
    const int v0  = c * CHUNK;
    const int cntv = min(CHUNK, NV - v0);   // 157 or 61

    // pack own chunk straight into LDS (no global packed[] round trip)
    if (tid < cntv) {
        int vi = b * NV + v0 + tid;
        float x = verts[3 * vi + 0];
        float y = verts[3 * vi + 1];
        float z = verts[3 * vi + 2];
        float w;
        if (visible[vi] == MAGIC) {
            w = x * x + y * y + z * z;   // q = |v|^2 - 2<p,v>; +|p|^2 later
        } else {
            w = 1e30f;                   // never wins the min
            atomicOr(&flags[b], 1u);     // device-scope, rare
        }
        shv[tid] = make_float4(-2.f * x, -2.f * y, -2.f * z, w);
    }

    float px[P], py[P], pz[P], mn[P];
    #pragma unroll
    for (int u = 0; u < P; ++u) {
        float4 p = bds[b * SMP + u * NTH + tid];
        px[u] = p.x; py[u] = p.y; pz[u] = p.z;
        mn[u] = 3.0e38f;
    }
    __syncthreads();

    #pragma unroll 4
    for (int j = 0; j < cntv; ++j) {
        float4 v = shv[j];               // LDS broadcast
        #pragma unroll
        for (int u = 0; u < P; ++u) {
            float q = fmaf(px[u], v.x,
                      fmaf(py[u], v.y,
                      fmaf(pz[u], v.z, v.w)));
            mn[u] = fminf(mn[u], q);
        }
    }
    #pragma unroll
    for (int u = 0; u < P; ++u)
        atomicMin(&minKeys[b * SMP + u * NTH + tid], enc_f32(mn[u]));

    // ticket: last block to finish does the final reduction
    __syncthreads();
    if (tid == 0) {
        __threadfence();
        lastBlk = (atomicAdd(cnt, 1u) == NBLK - 1);
    }
    __syncthreads();
    if (!lastBlk) return;

    // final: coherent atomic reads of keys, +|p|^2, penalty clamp, masked sum
    float sum = 0.0f;
    #pragma unroll
    for (int bb = 0; bb < BT; ++bb) {
        unsigned int fb = atomicOr(&flags[bb], 0u);   // coherent read
        for (int j = 0; j < SMP; j += NTH) {
            int i = bb * SMP + j + tid;
            unsigned int k = atomicAdd(&minKeys[i], 0u);  // coherent read
            float4 p = bds[i];
            float bs = fmaf(p.x, p.x, fmaf(p.y, p.y, p.z * p.z));
            float mnv = dec_f32(k) + bs;
            if (fb) mnv = fminf(mnv, 1000.0f);        // exact MASK_PENALTY
            sum = fmaf(mnv, p.w, sum);                // p.w = sample mask
        }
    }
    #pragma unroll
    for (int o = 32; o > 0; o >>= 1) sum += __shfl_down(sum, o, 64);
    if ((tid & 63) == 0) part[tid >> 6] = sum;
    __syncthreads();
    if (tid == 0)
        out[0] = (part[0] + part[1] + part[2] + part[3]) / (float)BT;
}

extern "C" void kernel_launch(void* const* d_in, const int* in_sizes, int n_in,
                              void* d_out, int out_size, void* d_ws, size_t ws_size,
                              hipStream_t stream) {
    const float*  verts = (const float*)d_in[0];   // (4,20000,3) f32
    const float4* bds   = (const float4*)d_in[1];  // (4,2048,4)  f32
    const int*    faces = (const int*)d_in[2];     // (4,40000,3) int
    const int4*   p2f   = (const int4*)d_in[3];    // (4,256,256,1) int
    float*        out   = (float*)d_out;

    char* ws = (char*)d_ws;
    unsigned int* visible = (unsigned int*)ws;                // 320,000 B
    unsigned int* minKeys = (unsigned int*)(ws + 320000);     //  32,768 B
    unsigned int* flags   = (unsigned int*)(ws + 352768);     //      16 B
    unsigned int* cnt     = (unsigned int*)(ws + 352784);     //       4 B

    vis_k<<<(NPIX / 4) / NTH, NTH, 0, stream>>>(
        (const int4*)p2f, faces, visible, minKeys, flags, cnt);
    mega_k<<<dim3(NCH, 1, BT), NTH, 0, stream>>>(
        verts, bds, visible, flags, minKeys, cnt, out);
}